// Round 1
// 3745.864 us; speedup vs baseline: 1.2261x; 1.2261x over previous
//
#include <hip/hip_runtime.h>
#include <math.h>

#define BB 2
#define TT 2048
#define CC 1024
#define HH 16
#define LL 6
#define VV 32000
#define DD 64
#define FFF 4096
#define MM (BB*TT)   // 4096 tokens

typedef __bf16 bf16;
typedef __bf16 bf16x8 __attribute__((ext_vector_type(8)));
typedef __bf16 bf16x4 __attribute__((ext_vector_type(4)));
typedef float  floatx4 __attribute__((ext_vector_type(4)));

__device__ __forceinline__ void async_copy16(const void* g, void* l) {
    __builtin_amdgcn_global_load_lds(
        (const __attribute__((address_space(1))) void*)g,
        (__attribute__((address_space(3))) void*)l, 16, 0, 0);
}

// ---------------------------------------------------------------------------
// GEMM: out = A @ B^T (+ epilogue). A:[MxK] lda, Bt:[NxK] ldb, bf16 in, fp32 acc.
// MODE 0: bf16 out = acc + bias[n]                  (QKV fused projection)
// MODE 3: bf16 out = gelu_exact(acc + bias[n])      (FF1)
// MODE 4: f32  out = acc + bias[n] + res[m*ldo+n]   (o-proj / FF2, in-place x)
// MODE 5: f32  out = acc, grouped-raster + XCD-chunked block remap (head)
// ---------------------------------------------------------------------------
template<int BM, int BN, int WM, int WN, int MODE>
__global__ __launch_bounds__(256) void gemm_bt(
    const bf16* __restrict__ A, int lda,
    const bf16* __restrict__ Bt, int ldb,
    int K, void* outp, int ldo,
    const float* __restrict__ bias, const float* res, float scale)
{
    constexpr int MI = WM / 16, NI = WN / 16;
    constexpr int WAVES_N = BN / WN;
    static_assert((BM % 64) == 0 && (BN % 64) == 0, "staging passes");
    static_assert((BM / WM) * (BN / WN) == 4, "4 waves");
    __shared__ __align__(16) bf16 As[BM * 32];
    __shared__ __align__(16) bf16 Bs[BN * 32];

    const int t   = threadIdx.x;
    int bn0 = blockIdx.x * BN;
    int bm0 = blockIdx.y * BM;
    const int z   = blockIdx.z;

    if (MODE == 5) {
        // L2-locality remap: XCD-bijective chunking (nwg % 8 == 0 here: 250*32),
        // then grouped raster: groups of 8 m-blocks, n varies fastest inside.
        const int nwg   = (int)(gridDim.x * gridDim.y);
        const int flat  = (int)(blockIdx.y * gridDim.x + blockIdx.x);
        const int chunk = nwg >> 3;
        const int wg    = (flat & 7) * chunk + (flat >> 3);
        const int GM    = 8;
        const int width = GM * (int)gridDim.x;     // 8 * 250 = 2000
        const int g     = wg / width;
        const int idx   = wg % width;
        bm0 = (g * GM + (idx % GM)) * BM;
        bn0 = (idx / GM) * BN;
    }

    const int lane = t & 63;
    const int ln   = lane & 15;
    const int quad = lane >> 4;
    const int wave = t >> 6;
    const int wm0  = (wave / WAVES_N) * WM;
    const int wn0  = (wave % WAVES_N) * WN;

    floatx4 acc[MI][NI] = {};

    const int arow = t >> 2;        // 0..63: row within 64-row staging pass
    const int acol = (t & 3) * 8;   // bf16 element offset within 32-wide k-tile

    for (int k0 = 0; k0 < K; k0 += 32) {
#pragma unroll
        for (int p = 0; p < BM / 64; ++p)
            async_copy16(A + (size_t)(bm0 + p * 64 + arow) * lda + k0 + acol,
                         As + p * 2048 + t * 8);
#pragma unroll
        for (int p = 0; p < BN / 64; ++p)
            async_copy16(Bt + (size_t)(bn0 + p * 64 + arow) * ldb + k0 + acol,
                         Bs + p * 2048 + t * 8);
        __syncthreads();   // drains vmcnt: LDS tiles ready
        bf16x8 af[MI], bfv[NI];
#pragma unroll
        for (int i = 0; i < MI; ++i)
            af[i] = *(const bf16x8*)(As + (wm0 + i * 16 + ln) * 32 + quad * 8);
#pragma unroll
        for (int j = 0; j < NI; ++j)
            bfv[j] = *(const bf16x8*)(Bs + (wn0 + j * 16 + ln) * 32 + quad * 8);
#pragma unroll
        for (int i = 0; i < MI; ++i)
#pragma unroll
            for (int j = 0; j < NI; ++j)
                acc[i][j] = __builtin_amdgcn_mfma_f32_16x16x32_bf16(
                    af[i], bfv[j], acc[i][j], 0, 0, 0);
        __syncthreads();   // all reads done before next staging overwrite
    }

#pragma unroll
    for (int i = 0; i < MI; ++i) {
#pragma unroll
        for (int j = 0; j < NI; ++j) {
            const int n = bn0 + wn0 + j * 16 + ln;
            float bv = 0.0f;
            if (MODE == 0 || MODE == 3 || MODE == 4) bv = bias[n];
#pragma unroll
            for (int r = 0; r < 4; ++r) {
                const int m = bm0 + wm0 + i * 16 + quad * 4 + r;
                float v = acc[i][j][r];
                if (MODE == 0 || MODE == 3 || MODE == 4) v += bv;
                if (MODE == 3) v = 0.5f * v * (1.0f + erff(v * 0.70710678118654752f));
                if (MODE == 0 || MODE == 3) {
                    ((bf16*)outp)[(size_t)m * ldo + n] = (bf16)v;
                } else if (MODE == 4) {
                    float* o = (float*)outp;
                    o[(size_t)m * ldo + n] = v + res[(size_t)m * ldo + n];
                } else {
                    ((float*)outp)[(size_t)m * ldo + n] = v;
                }
            }
        }
    }
}

// ---------------------------------------------------------------------------
// Fused flash attention: O = softmax(Q K^T / 8) V for one (b,h), 64 Q-rows/block.
// 4 waves x 16 Q-rows; 16 KV-tiles of 128. K,V^T staged via global_load_lds with
// pre-swizzled SOURCE columns (LDS dest linear); P via wave-private swizzled LDS.
// ---------------------------------------------------------------------------
__global__ __launch_bounds__(256) void attn_kernel(
    const bf16* __restrict__ qkv, const bf16* __restrict__ vT,
    bf16* __restrict__ obuf)
{
    __shared__ __align__(16) bf16 Ks[128 * 64];   // [kvrow][k]  128B rows, 16B-slot XOR (row&7)
    __shared__ __align__(16) bf16 Vs[64 * 128];   // [d][s]      256B rows, 16B-slot XOR (row&15)
    __shared__ __align__(16) bf16 Ps[64 * 128];   // [qrow][s]   256B rows, 16B-slot XOR (row&15)

    const int t    = threadIdx.x;
    const int lane = t & 63;
    const int ln   = lane & 15;
    const int quad = lane >> 4;
    const int w    = t >> 6;
    const int q0   = blockIdx.x * 64;
    const int z    = blockIdx.y;          // b*HH + h
    const int b    = z >> 4;
    const int h    = z & 15;

    // Q A-fragments (rows w*16+ln, k = s*32 + quad*8), pre-scaled by 1/8 (exact pow2)
    const bf16* qp = qkv + (size_t)(b * TT + q0 + w * 16 + ln) * (3 * CC) + h * DD + quad * 8;
    bf16x8 qf[2];
#pragma unroll
    for (int s = 0; s < 2; ++s) {
        bf16x8 raw = *(const bf16x8*)(qp + s * 32);
#pragma unroll
        for (int e = 0; e < 8; ++e) qf[s][e] = (bf16)((float)raw[e] * 0.125f);
    }

    floatx4 acc_o[4] = {};
    float m_r[4], l_r[4];
#pragma unroll
    for (int r = 0; r < 4; ++r) { m_r[r] = -1e30f; l_r[r] = 0.0f; }

    // staging geometry (source col pre-XOR'd so swizzled reads see linear data)
    const int krow = t >> 3;                      // 0..31 (K: 8 lanes/row of 128B)
    const int kcol = ((t & 7) ^ (krow & 7)) * 8;  // element offset in [0,64)
    const bf16* kg = qkv + (size_t)b * TT * (3 * CC) + CC + h * DD + kcol;
    const int vrow = t >> 4;                      // 0..15 (V^T: 16 lanes/row of 256B)
    const int vcol = ((t & 15) ^ (vrow & 15)) * 8;
    const bf16* vg = vT + (size_t)z * DD * TT + vcol;

    for (int j = 0; j < 16; ++j) {
#pragma unroll
        for (int p = 0; p < 4; ++p)
            async_copy16(kg + (size_t)(j * 128 + p * 32 + krow) * (3 * CC),
                         Ks + p * 2048 + t * 8);
#pragma unroll
        for (int p = 0; p < 4; ++p)
            async_copy16(vg + (size_t)(p * 16 + vrow) * TT + j * 128,
                         Vs + p * 2048 + t * 8);
        __syncthreads();   // drains vmcnt: K/V tiles ready

        // ---- S = (Q/8) @ K_j^T : 16 x 128 per wave ----
        floatx4 acc_s[8];
#pragma unroll
        for (int nj = 0; nj < 8; ++nj) acc_s[nj] = floatx4{0.f, 0.f, 0.f, 0.f};
#pragma unroll
        for (int s = 0; s < 2; ++s) {
#pragma unroll
            for (int nj = 0; nj < 8; ++nj) {
                const int row = nj * 16 + ln;
                const int cb  = (s * 64 + quad * 16) ^ ((row & 7) << 4);
                bf16x8 kf = *(const bf16x8*)((const char*)Ks + row * 128 + cb);
                acc_s[nj] = __builtin_amdgcn_mfma_f32_16x16x32_bf16(qf[s], kf, acc_s[nj], 0, 0, 0);
            }
        }

        // ---- online softmax: rows w*16+quad*4+r, cols spread over (nj, ln) ----
#pragma unroll
        for (int r = 0; r < 4; ++r) {
            float v = fmaxf(fmaxf(fmaxf(acc_s[0][r], acc_s[1][r]), fmaxf(acc_s[2][r], acc_s[3][r])),
                            fmaxf(fmaxf(acc_s[4][r], acc_s[5][r]), fmaxf(acc_s[6][r], acc_s[7][r])));
            v = fmaxf(v, __shfl_xor(v, 1, 64));
            v = fmaxf(v, __shfl_xor(v, 2, 64));
            v = fmaxf(v, __shfl_xor(v, 4, 64));
            v = fmaxf(v, __shfl_xor(v, 8, 64));
            const float mn   = fmaxf(m_r[r], v);
            const float corr = __expf(m_r[r] - mn);
            m_r[r] = mn;
#pragma unroll
            for (int nd = 0; nd < 4; ++nd) acc_o[nd][r] *= corr;
            const int prow = w * 16 + quad * 4 + r;
            float rs = 0.0f;
#pragma unroll
            for (int nj = 0; nj < 8; ++nj) {
                float pv = __expf(acc_s[nj][r] - mn);
                rs += pv;
                const int cb = (2 * (nj * 16 + ln)) ^ ((prow & 15) << 4);
                *(bf16*)((char*)Ps + prow * 256 + cb) = (bf16)pv;
            }
            rs += __shfl_xor(rs, 1, 64);
            rs += __shfl_xor(rs, 2, 64);
            rs += __shfl_xor(rs, 4, 64);
            rs += __shfl_xor(rs, 8, 64);
            l_r[r] = l_r[r] * corr + rs;
        }

        // ---- O += P @ V_j  (P is wave-private: rows w*16..w*16+15) ----
#pragma unroll
        for (int s = 0; s < 4; ++s) {
            const int prow = w * 16 + ln;
            const int pcb  = (s * 64 + quad * 16) ^ ((prow & 15) << 4);
            bf16x8 pa = *(const bf16x8*)((const char*)Ps + prow * 256 + pcb);
#pragma unroll
            for (int nd = 0; nd < 4; ++nd) {
                const int drow = nd * 16 + ln;
                const int vcb  = (s * 64 + quad * 16) ^ ((drow & 15) << 4);
                bf16x8 vf = *(const bf16x8*)((const char*)Vs + drow * 256 + vcb);
                acc_o[nd] = __builtin_amdgcn_mfma_f32_16x16x32_bf16(pa, vf, acc_o[nd], 0, 0, 0);
            }
        }
        __syncthreads();   // all K/V/P reads done before next staging overwrite
    }

    const size_t orow = (size_t)(b * TT + q0 + w * 16 + quad * 4);
#pragma unroll
    for (int r = 0; r < 4; ++r) {
        const float inv = 1.0f / l_r[r];
#pragma unroll
        for (int nd = 0; nd < 4; ++nd)
            obuf[(orow + r) * CC + h * DD + nd * 16 + ln] = (bf16)(acc_o[nd][r] * inv);
    }
}

// --------------------- weight transpose + fp32 -> bf16 ---------------------
// in: [z][R][Cc] fp32 -> out: [z][Cc][R] bf16
__global__ void wtrans_kernel(const float* __restrict__ in, bf16* __restrict__ out,
                              int R, int Cc, long long in_bs, long long out_bs)
{
    __shared__ float tile[32][33];
    const float* ip = in  + (size_t)blockIdx.z * in_bs;
    bf16*        op = out + (size_t)blockIdx.z * out_bs;
    int c0 = blockIdx.x * 32, r0 = blockIdx.y * 32;
    int tx = threadIdx.x, ty = threadIdx.y;
#pragma unroll
    for (int r = 0; r < 4; ++r)
        tile[ty + r * 8][tx] = ip[(size_t)(r0 + ty + r * 8) * Cc + c0 + tx];
    __syncthreads();
#pragma unroll
    for (int r = 0; r < 4; ++r)
        op[(size_t)(c0 + ty + r * 8) * R + r0 + tx] = (bf16)tile[tx][ty + r * 8];
}

// transpose V slice of qkv -> vT[z][d][s]   (z = b*H + h)
__global__ void vtrans_kernel(const bf16* __restrict__ qkv, bf16* __restrict__ vT)
{
    __shared__ bf16 tile[32][33];
    int z = blockIdx.z;
    int b = z / HH, h = z % HH;
    int s0 = blockIdx.x * 32, d0 = blockIdx.y * 32;
    int tx = threadIdx.x, ty = threadIdx.y;
    const bf16* in = qkv + (size_t)b * TT * 3 * CC + 2 * CC + h * DD;
#pragma unroll
    for (int r = 0; r < 4; ++r)
        tile[ty + r * 8][tx] = in[(size_t)(s0 + ty + r * 8) * 3 * CC + d0 + tx];
    __syncthreads();
    bf16* o = vT + (size_t)z * DD * TT;
#pragma unroll
    for (int r = 0; r < 4; ++r)
        o[(size_t)(d0 + ty + r * 8) * TT + s0 + tx] = tile[tx][ty + r * 8];
}

__global__ void bias_concat(const float* __restrict__ bq, const float* __restrict__ bk,
                            const float* __restrict__ bv, float* __restrict__ o)
{
    int l = blockIdx.x, c = threadIdx.x;
    o[(size_t)l * 3 * CC + c]          = bq[(size_t)l * CC + c];
    o[(size_t)l * 3 * CC + CC + c]     = bk[(size_t)l * CC + c];
    o[(size_t)l * 3 * CC + 2 * CC + c] = bv[(size_t)l * CC + c];
}

__global__ void embed_kernel(const int* __restrict__ src, const float* __restrict__ semb,
                             const float* __restrict__ pemb, float* __restrict__ x)
{
    int m = blockIdx.x, t = threadIdx.x;
    int tok = src[m];
    int pos = m % TT;
    float4 e = ((const float4*)(semb + (size_t)tok * CC))[t];
    float4 p = ((const float4*)(pemb + (size_t)pos * CC))[t];
    float4 o; o.x = e.x + p.x; o.y = e.y + p.y; o.z = e.z + p.z; o.w = e.w + p.w;
    ((float4*)(x + (size_t)m * CC))[t] = o;
}

// LayerNorm row (C=1024) fp32 -> bf16, 256 threads, float4 per thread
__global__ __launch_bounds__(256) void ln_kernel(
    const float* __restrict__ x, const float* __restrict__ w,
    const float* __restrict__ b, bf16* __restrict__ out)
{
    __shared__ float red[4];
    int row = blockIdx.x, t = threadIdx.x;
    float4 v = ((const float4*)(x + (size_t)row * CC))[t];
    float s = v.x + v.y + v.z + v.w;
    for (int off = 32; off; off >>= 1) s += __shfl_xor(s, off, 64);
    if ((t & 63) == 0) red[t >> 6] = s;
    __syncthreads();
    s = red[0] + red[1] + red[2] + red[3];
    float mean = s * (1.0f / CC);
    float dx = v.x - mean, dy = v.y - mean, dz = v.z - mean, dw = v.w - mean;
    float q = dx * dx + dy * dy + dz * dz + dw * dw;
    __syncthreads();
    for (int off = 32; off; off >>= 1) q += __shfl_xor(q, off, 64);
    if ((t & 63) == 0) red[t >> 6] = q;
    __syncthreads();
    q = red[0] + red[1] + red[2] + red[3];
    float rstd = rsqrtf(q * (1.0f / CC) + 1e-5f);
    float4 wv = ((const float4*)w)[t];
    float4 bv = ((const float4*)b)[t];
    bf16x4 ov;
    ov[0] = (bf16)(dx * rstd * wv.x + bv.x);
    ov[1] = (bf16)(dy * rstd * wv.y + bv.y);
    ov[2] = (bf16)(dz * rstd * wv.z + bv.z);
    ov[3] = (bf16)(dw * rstd * wv.w + bv.w);
    *(bf16x4*)(out + (size_t)row * CC + t * 4) = ov;
}

// ---------------------------------------------------------------------------
extern "C" void kernel_launch(void* const* d_in, const int* in_sizes, int n_in,
                              void* d_out, int out_size, void* d_ws, size_t ws_size,
                              hipStream_t stream)
{
    const int*   src     = (const int*)  d_in[0];
    const float* src_emb = (const float*)d_in[1];
    const float* pos_emb = (const float*)d_in[2];
    const float* ln1_w   = (const float*)d_in[3];
    const float* ln1_b   = (const float*)d_in[4];
    const float* wq      = (const float*)d_in[5];
    const float* bq      = (const float*)d_in[6];
    const float* wk      = (const float*)d_in[7];
    const float* bk      = (const float*)d_in[8];
    const float* wv      = (const float*)d_in[9];
    const float* bv      = (const float*)d_in[10];
    const float* wo      = (const float*)d_in[11];
    const float* bo      = (const float*)d_in[12];
    const float* ln2_w   = (const float*)d_in[13];
    const float* ln2_b   = (const float*)d_in[14];
    const float* w1      = (const float*)d_in[15];
    const float* b1      = (const float*)d_in[16];
    const float* w2      = (const float*)d_in[17];
    const float* b2      = (const float*)d_in[18];
    const float* lnf_w   = (const float*)d_in[19];
    const float* lnf_b   = (const float*)d_in[20];
    const float* head_w  = (const float*)d_in[21];

    // --- scratch carved out of d_out (dead before head GEMM overwrites all) ---
    char* ob = (char*)d_out;
    bf16* wqkvT  = (bf16*)(ob);                  // L*3C*C        37,748,736 B
    bf16* woT    = (bf16*)(ob +  37748736);      // L*C*C         12,582,912 B
    bf16* w1T    = (bf16*)(ob +  50331648);      // L*FF*C        50,331,648 B
    bf16* w2T    = (bf16*)(ob + 100663296);      // L*C*FF        50,331,648 B
    bf16* ff     = (bf16*)(ob + 419430400);      // M*FF          33,554,432 B
    bf16* qkv    = (bf16*)(ob + 452984832);      // M*3C          25,165,824 B
    bf16* vT     = (bf16*)(ob + 478150656);      // B*H*D*T        8,388,608 B
    bf16* obuf   = (bf16*)(ob + 486539264);      // M*C            8,388,608 B
    // total 494,927,872 B <= out 524,288,000 B

    // --- persistent-through-head scratch in ws ---
    char* wb = (char*)d_ws;
    bf16*  headT = (bf16*)(wb);                  // V*C           65,536,000 B
    float* x     = (float*)(wb + 65536000);      // M*C fp32      16,777,216 B
    bf16*  h     = (bf16*)(wb + 82313216);       // M*C            8,388,608 B
    float* bqkv  = (float*)(wb + 90701824);      // L*3C              73,728 B
    if (ws_size < 90775552) return;              // insufficient scratch

    dim3 tb(32, 8, 1);
    long long cc = (long long)CC * CC, cf = (long long)CC * FFF;
    wtrans_kernel<<<dim3(32, 32, LL), tb, 0, stream>>>(wq, wqkvT,              CC, CC, cc, 3 * cc);
    wtrans_kernel<<<dim3(32, 32, LL), tb, 0, stream>>>(wk, wqkvT + CC * CC,    CC, CC, cc, 3 * cc);
    wtrans_kernel<<<dim3(32, 32, LL), tb, 0, stream>>>(wv, wqkvT + 2 * CC * CC, CC, CC, cc, 3 * cc);
    wtrans_kernel<<<dim3(32, 32, LL), tb, 0, stream>>>(wo, woT, CC, CC, cc, cc);
    wtrans_kernel<<<dim3(FFF / 32, CC / 32, LL), tb, 0, stream>>>(w1, w1T, CC, FFF, cf, cf);
    wtrans_kernel<<<dim3(CC / 32, FFF / 32, LL), tb, 0, stream>>>(w2, w2T, FFF, CC, cf, cf);
    wtrans_kernel<<<dim3(VV / 32, CC / 32, 1), tb, 0, stream>>>(head_w, headT, CC, VV, 0, 0);
    bias_concat<<<LL, CC, 0, stream>>>(bq, bk, bv, bqkv);
    embed_kernel<<<MM, 256, 0, stream>>>(src, src_emb, pos_emb, x);

    for (int l = 0; l < LL; ++l) {
        ln_kernel<<<MM, 256, 0, stream>>>(x, ln1_w + l * CC, ln1_b + l * CC, h);
        // fused QKV projection: [4096 x 3072] = h @ [wq|wk|wv]
        gemm_bt<128, 128, 64, 64, 0><<<dim3(3 * CC / 128, MM / 128, 1), 256, 0, stream>>>(
            h, CC, wqkvT + (size_t)l * 3 * CC * CC, CC, CC,
            qkv, 3 * CC, bqkv + l * 3 * CC, nullptr, 1.0f);
        vtrans_kernel<<<dim3(TT / 32, DD / 32, BB * HH), tb, 0, stream>>>(qkv, vT);
        // fused flash attention: scores + softmax + PV in one kernel
        attn_kernel<<<dim3(TT / 64, BB * HH, 1), 256, 0, stream>>>(qkv, vT, obuf);
        // x = x + O @ wo + bo   (in-place residual)
        gemm_bt<128, 128, 64, 64, 4><<<dim3(CC / 128, MM / 128, 1), 256, 0, stream>>>(
            obuf, CC, woT + (size_t)l * CC * CC, CC, CC,
            x, CC, bo + l * CC, x, 1.0f);
        ln_kernel<<<MM, 256, 0, stream>>>(x, ln2_w + l * CC, ln2_b + l * CC, h);
        // ff = gelu(h @ w1 + b1)
        gemm_bt<128, 128, 64, 64, 3><<<dim3(FFF / 128, MM / 128, 1), 256, 0, stream>>>(
            h, CC, w1T + (size_t)l * CC * FFF, CC, CC,
            ff, FFF, b1 + l * FFF, nullptr, 1.0f);
        // x = x + ff @ w2 + b2
        gemm_bt<128, 128, 64, 64, 4><<<dim3(CC / 128, MM / 128, 1), 256, 0, stream>>>(
            ff, FFF, w2T + (size_t)l * CC * FFF, FFF, FFF,
            x, CC, b2 + l * CC, x, 1.0f);
    }
    ln_kernel<<<MM, 256, 0, stream>>>(x, lnf_w, lnf_b, h);
    // logits = h @ head_w   -> overwrites ALL of d_out last
    gemm_bt<128, 128, 64, 64, 5><<<dim3(VV / 128, MM / 128, 1), 256, 0, stream>>>(
        h, CC, headT, CC, CC,
        d_out, VV, nullptr, nullptr, 1.0f);
}